// Round 1
// baseline (376.071 us; speedup 1.0000x reference)
//
#include <hip/hip_runtime.h>

// HiPPO-LegS scan — round 7: latency attack on the round-6 pipeline.
//  * __launch_bounds__(320,3) everywhere: lift the 92-VGPR cap that forced the
//    compiler to serialize the chain_step load pipeline.
//  * Passthrough-free Kogge-Stone: j<D nodes exit; readers select source buffer
//    per node class L=min(pow2floor(j'),D/2) (A for L in {0,2,8}, B for {1,4}).
//  * kgroup (serial depth 15) replaced by 4 tiny group-level KS phases over the
//    16 group totals, stored in stale B-buffer slots (16t+0 / 16t+2).
//  * k3 h-split: 512 blocks, 16 batch rows each (state_step_h), halves span.
// Pipeline: k1(512) -> ks_np<1,2,4,8>(512) -> gks<1,2,4,8>(32) -> k3h(512).
// Workspace ~41.9 MB (A set + B set only; E buffers gone).

#define LDK 136  // f16 k-stride of LDS state rows

using f16 = _Float16;
typedef __attribute__((ext_vector_type(8))) f16 f16x8;
typedef __attribute__((ext_vector_type(4))) float f32x4;

__device__ __forceinline__ f32x4 mfma3(f16x8 ah, f16x8 al, f16x8 bh, f16x8 bl,
                                       f32x4 c) {
  c = __builtin_amdgcn_mfma_f32_16x16x32_f16(ah, bh, c, 0, 0, 0);
  c = __builtin_amdgcn_mfma_f32_16x16x32_f16(ah, bl, c, 0, 0, 0);
  c = __builtin_amdgcn_mfma_f32_16x16x32_f16(al, bh, c, 0, 0, 0);
  return c;
}

__device__ __forceinline__ void split8(const float* v, f16x8& h, f16x8& l) {
#pragma unroll
  for (int j = 0; j < 8; ++j) {
    const float x = v[j];
    const f16 hh = (f16)x;
    h[j] = hh;
    l[j] = (f16)(x - (float)hh);
  }
}

// global m-tile owned by (h, slot): h=0 -> {0,7,1,6}, h=1 -> {2,5,3,4}
__device__ __forceinline__ int slot2mt(int h, int slot) {
  if (h == 0) return (slot & 1) ? 7 - (slot >> 1) : (slot >> 1);
  return (slot & 1) ? 5 - (slot >> 1) : 2 + (slot >> 1);
}

// ---------------------------------------------------------------------------
// chain_step: P' (LDS, rows = this block's 5 m-tiles: 4 matrix + 1 w) updates
// P' <- P' * B^T where B is 128x128 lower-tri read from global (f32 or f16 pair).
// wave wv (0..4) owns m-tile `mt` (local rows wv*16..+15). 2 barriers.
// EXTRA==1: w-rows += bv (x) outer (aux0=x+l*32, aux1=Bv+l*128)
// EXTRA==2: w-rows += w_add f32 [n][32b] (aux0)
template <bool F32B, int EXTRA>
__device__ __forceinline__ void chain_step(const float* __restrict__ Bf,
                                           const f16* __restrict__ Bh16,
                                           const f16* __restrict__ Bl16,
                                           const float* __restrict__ aux0,
                                           const float* __restrict__ aux1,
                                           f16* __restrict__ Ph,
                                           f16* __restrict__ Pl,
                                           int wv, int mt) {
  const int lane = threadIdx.x & 63;
  const int lr = lane & 15, q = lane >> 4;
  const bool wrow = (mt >= 8);
  const int ktA0 = wrow ? 0 : (mt >> 1);
  f16x8 ah[4], al[4];
#pragma unroll
  for (int kt = 0; kt < 4; ++kt) {
    if (kt >= ktA0) {
      const int off = (wv * 16 + lr) * LDK + kt * 32 + q * 8;
      ah[kt] = *(const f16x8*)(Ph + off);
      al[kt] = *(const f16x8*)(Pl + off);
    }
  }
  f32x4 acc[8];
#pragma unroll
  for (int nt = 0; nt < 8; ++nt) acc[nt] = (f32x4){0.f, 0.f, 0.f, 0.f};

  float raw[2][4][8];
  f16x8 b16h[2][4], b16l[2][4];
  f16x8 ch[4], cl[4];

  auto loadB = [&](int nt, int s) {
#pragma unroll
    for (int kt = 0; kt < 4; ++kt) {
      if (kt >= ktA0 && kt <= (nt >> 1)) {
        if (F32B) {
          const float* p = Bf + (nt * 16 + lr) * 128 + kt * 32 + q * 8;
          *(float4*)&raw[s][kt][0] = *(const float4*)p;
          *(float4*)&raw[s][kt][4] = *(const float4*)(p + 4);
        } else {
          const int o = (nt * 16 + lr) * 128 + kt * 32 + q * 8;
          b16h[s][kt] = *(const f16x8*)(Bh16 + o);
          b16l[s][kt] = *(const f16x8*)(Bl16 + o);
        }
      }
    }
  };

  if (wrow || mt == 0) loadB(0, 0);
#pragma unroll
  for (int nt = 0; nt < 8; ++nt) {
    const int cur = nt & 1;
    if (nt < 7 && (wrow || (nt + 1) >= mt)) loadB(nt + 1, cur ^ 1);
    if (wrow || nt >= mt) {
      if (F32B) {
#pragma unroll
        for (int kt = 0; kt < 4; ++kt)
          if (kt >= ktA0 && kt <= (nt >> 1)) split8(raw[cur][kt], ch[kt], cl[kt]);
#pragma unroll
        for (int kt = 0; kt < 4; ++kt)
          if (kt >= ktA0 && kt <= (nt >> 1))
            acc[nt] = mfma3(ah[kt], al[kt], ch[kt], cl[kt], acc[nt]);
      } else {
#pragma unroll
        for (int kt = 0; kt < 4; ++kt)
          if (kt >= ktA0 && kt <= (nt >> 1))
            acc[nt] = mfma3(ah[kt], al[kt], b16h[cur][kt], b16l[cur][kt], acc[nt]);
      }
    }
  }
  __syncthreads();
#pragma unroll
  for (int nt = 0; nt < 8; ++nt) {
    if (!(wrow || nt >= mt)) continue;
    float v[4] = {acc[nt][0], acc[nt][1], acc[nt][2], acc[nt][3]};
    if (wrow) {
      const int b0 = (mt - 8) * 16 + q * 4;
      if (EXTRA == 2) {
        const float4 w4 = *(const float4*)(aux0 + (nt * 16 + lr) * 32 + b0);
        v[0] += w4.x; v[1] += w4.y; v[2] += w4.z; v[3] += w4.w;
      } else if (EXTRA == 1) {
        const float4 x4 = *(const float4*)(aux0 + b0);
        const float bn = aux1[nt * 16 + lr];
        v[0] += bn * x4.x; v[1] += bn * x4.y; v[2] += bn * x4.z; v[3] += bn * x4.w;
      }
    }
#pragma unroll
    for (int r = 0; r < 4; ++r) {
      const int o = (wv * 16 + q * 4 + r) * LDK + nt * 16 + lr;
      const f16 hh = (f16)v[r];
      Ph[o] = hh;
      Pl[o] = (f16)(v[r] - (float)hh);
    }
  }
  __syncthreads();
}

// copy P' (= result^T in LDS) out as PLAIN M (f16 hi/lo) + w (f32 [n][32])
__device__ __forceinline__ void chain_copyout(const f16* __restrict__ Ph,
                                              const f16* __restrict__ Pl, int h,
                                              f16* __restrict__ oMh,
                                              f16* __restrict__ oMl,
                                              float* __restrict__ oW) {
  const int tid = threadIdx.x;
  for (int t = tid; t < 1024; t += 320) {
    const int i = t >> 3;
    const int slot = (t >> 1) & 3;
    const int half = t & 1;
    const int mtg = slot2mt(h, slot);
    f16x8 hv, lv;
#pragma unroll
    for (int e = 0; e < 8; ++e) {
      hv[e] = Ph[(slot * 16 + half * 8 + e) * LDK + i];
      lv[e] = Pl[(slot * 16 + half * 8 + e) * LDK + i];
    }
    *(f16x8*)(oMh + i * 128 + mtg * 16 + half * 8) = hv;
    *(f16x8*)(oMl + i * 128 + mtg * 16 + half * 8) = lv;
  }
  for (int t = tid; t < 512; t += 320) {
    const int n = t >> 2, b4 = (t & 3) * 4;
    float4 o;
    float* po = (float*)&o;
#pragma unroll
    for (int e = 0; e < 4; ++e)
      po[e] = (float)Ph[(64 + b4 + e) * LDK + n] + (float)Pl[(64 + b4 + e) * LDK + n];
    *(float4*)(oW + n * 32 + h * 16 + b4) = o;
  }
}

// P'-init: load prev node's plain M + W into LDS (transposed). Trailing barrier.
__device__ __forceinline__ void load_prev_to_P(const f16* pMh, const f16* pMl,
                                               const float* pW, int h,
                                               f16* Ph, f16* Pl) {
  const int tid = threadIdx.x;
  for (int t = tid; t < 1024; t += 320) {
    const int k = t >> 3, u = t & 7;
    const int slot = u >> 1, half = u & 1;
    const int mtg = slot2mt(h, slot);
    const f16x8 hv = *(const f16x8*)(pMh + k * 128 + mtg * 16 + half * 8);
    const f16x8 lv = *(const f16x8*)(pMl + k * 128 + mtg * 16 + half * 8);
#pragma unroll
    for (int e = 0; e < 8; ++e) {
      Ph[(slot * 16 + half * 8 + e) * LDK + k] = hv[e];
      Pl[(slot * 16 + half * 8 + e) * LDK + k] = lv[e];
    }
  }
  for (int t = tid; t < 2048; t += 320) {
    const int n = t >> 4, b = t & 15;
    const float wv0 = pW[n * 32 + h * 16 + b];
    const f16 hh = (f16)wv0;
    Ph[(64 + b) * LDK + n] = hh;
    Pl[(64 + b) * LDK + n] = (f16)(wv0 - (float)hh);
  }
  __syncthreads();
}

// ---------------------------------------------------------------------------
// state_step_h: 16-row state s^T (LDS 16xLDK f16 hi/lo) <- s^T * B^T (+adds).
// 320 threads; waves 0..3 compute (nts {wv,7-wv}), wave 4 barriers only.
template <bool F32B, int EXTRA>
__device__ __forceinline__ void state_step_h(const float* __restrict__ Bf,
                                             const f16* __restrict__ Bh16,
                                             const f16* __restrict__ Bl16,
                                             const float* __restrict__ aux0,
                                             const float* __restrict__ aux1,
                                             f16* __restrict__ Sh,
                                             f16* __restrict__ Sl,
                                             float* __restrict__ outp, int h) {
  const int tid = threadIdx.x;
  const int wv4 = tid >> 6;
  const bool act = (wv4 < 4);
  const int wv = wv4 & 3;
  const int lane = tid & 63, lr = lane & 15, q = lane >> 4;
  const int nts[2] = {wv, 7 - wv};
  const int ktAmax = (7 - wv) >> 1;
  f16x8 ah[4], al[4];
  f16x8 bh[2][4], bl[2][4];
  f32x4 acc[2];
  if (act) {
#pragma unroll
    for (int kt = 0; kt < 4; ++kt)
      if (kt <= ktAmax) {
        const int off = lr * LDK + kt * 32 + q * 8;
        ah[kt] = *(const f16x8*)(Sh + off);
        al[kt] = *(const f16x8*)(Sl + off);
      }
    if (F32B) {
      float raw[2][4][8];
#pragma unroll
      for (int ni = 0; ni < 2; ++ni) {
        const int nt = nts[ni];
#pragma unroll
        for (int kt = 0; kt < 4; ++kt)
          if (kt <= (nt >> 1)) {
            const float* p = Bf + (nt * 16 + lr) * 128 + kt * 32 + q * 8;
            *(float4*)&raw[ni][kt][0] = *(const float4*)p;
            *(float4*)&raw[ni][kt][4] = *(const float4*)(p + 4);
          }
      }
#pragma unroll
      for (int ni = 0; ni < 2; ++ni) {
        const int nt = nts[ni];
#pragma unroll
        for (int kt = 0; kt < 4; ++kt)
          if (kt <= (nt >> 1)) split8(raw[ni][kt], bh[ni][kt], bl[ni][kt]);
      }
    } else {
#pragma unroll
      for (int ni = 0; ni < 2; ++ni) {
        const int nt = nts[ni];
#pragma unroll
        for (int kt = 0; kt < 4; ++kt)
          if (kt <= (nt >> 1)) {
            const int o = (nt * 16 + lr) * 128 + kt * 32 + q * 8;
            bh[ni][kt] = *(const f16x8*)(Bh16 + o);
            bl[ni][kt] = *(const f16x8*)(Bl16 + o);
          }
      }
    }
#pragma unroll
    for (int ni = 0; ni < 2; ++ni) acc[ni] = (f32x4){0.f, 0.f, 0.f, 0.f};
#pragma unroll
    for (int ni = 0; ni < 2; ++ni) {
      const int nt = nts[ni];
#pragma unroll
      for (int kt = 0; kt < 4; ++kt)
        if (kt <= (nt >> 1))
          acc[ni] = mfma3(ah[kt], al[kt], bh[ni][kt], bl[ni][kt], acc[ni]);
    }
  }
  __syncthreads();
  if (act) {
#pragma unroll
    for (int ni = 0; ni < 2; ++ni) {
      const int nt = nts[ni];
      float v[4] = {acc[ni][0], acc[ni][1], acc[ni][2], acc[ni][3]};
      const int bq = q * 4;
      if (EXTRA == 2) {
        const float4 w4 = *(const float4*)(aux0 + (nt * 16 + lr) * 32 + h * 16 + bq);
        v[0] += w4.x; v[1] += w4.y; v[2] += w4.z; v[3] += w4.w;
      } else if (EXTRA == 1) {
        const float4 x4 = *(const float4*)(aux0 + h * 16 + bq);
        const float bn = aux1[nt * 16 + lr];
        v[0] += bn * x4.x; v[1] += bn * x4.y; v[2] += bn * x4.z; v[3] += bn * x4.w;
      }
      if (outp) {
#pragma unroll
        for (int r = 0; r < 4; ++r)
          outp[(h * 16 + bq + r) * 128 + nt * 16 + lr] = v[r];
      }
#pragma unroll
      for (int r = 0; r < 4; ++r) {
        const int o = (bq + r) * LDK + nt * 16 + lr;
        const f16 hh = (f16)v[r];
        Sh[o] = hh;
        Sl[o] = (f16)(v[r] - (float)hh);
      }
    }
  }
  __syncthreads();
}

// ---------------------------------------------------------------------------
// K1: chunk units. grid 512 (c = bid>>1, h = bid&1), 320 threads. writes set A.
__global__ __launch_bounds__(320, 3) void k1_chunks(const float* __restrict__ A,
                                                    const float* __restrict__ x,
                                                    const float* __restrict__ Bv,
                                                    f16* __restrict__ Mh,
                                                    f16* __restrict__ Ml,
                                                    float* __restrict__ Wf) {
  __shared__ f16 Ph[80 * LDK], Pl[80 * LDK];
  const int tid = threadIdx.x;
  const int c = blockIdx.x >> 1, h = blockIdx.x & 1;
  const int l0 = 4 * c;
  const float* A0 = A + (size_t)l0 * 16384;
  for (int t = tid; t < 2048; t += 320) {
    const int k = t >> 4, u = t & 15;
    const int slot = u >> 2, fo = (u & 3) * 4;
    const int mtg = slot2mt(h, slot);
    const float4 v = *(const float4*)(A0 + k * 128 + mtg * 16 + fo);
    const float vv[4] = {v.x, v.y, v.z, v.w};
#pragma unroll
    for (int e = 0; e < 4; ++e) {
      const f16 hh = (f16)vv[e];
      Ph[(slot * 16 + fo + e) * LDK + k] = hh;
      Pl[(slot * 16 + fo + e) * LDK + k] = (f16)(vv[e] - (float)hh);
    }
  }
  for (int t = tid; t < 512; t += 320) {
    const int b = t >> 5, n4 = (t & 31) * 4;
    const float xb = x[l0 * 32 + h * 16 + b];
#pragma unroll
    for (int e = 0; e < 4; ++e) {
      const float u = xb * Bv[l0 * 128 + n4 + e];
      const f16 hh = (f16)u;
      Ph[(64 + b) * LDK + n4 + e] = hh;
      Pl[(64 + b) * LDK + n4 + e] = (f16)(u - (float)hh);
    }
  }
  __syncthreads();
  const int wv = tid >> 6;
  const int mt = (wv == 4) ? (8 + h) : slot2mt(h, wv);
#pragma unroll 1
  for (int j = 1; j <= 3; ++j) {
    const int l = l0 + j;
    chain_step<true, 1>(A + (size_t)l * 16384, nullptr, nullptr, x + l * 32,
                        Bv + l * 128, Ph, Pl, wv, mt);
  }
  chain_copyout(Ph, Pl, h, Mh + (size_t)c * 16384, Ml + (size_t)c * 16384,
                Wf + (size_t)c * 4096);
}

// ---------------------------------------------------------------------------
// Passthrough-free Kogge-Stone level D over within-group (16) prefixes.
// grid 512, 320 thr; blocks with j<D exit. Source buffer per node class:
// L = min(pow2floor(j'), D/2); L in {0,2,8} -> set A, {1,4} -> set B.
template <int D>
__global__ __launch_bounds__(320, 3) void ks_np(const f16* MhA, const f16* MlA,
                                                const float* WA, const f16* MhB,
                                                const f16* MlB, const float* WB,
                                                f16* oMh, f16* oMl, float* oW) {
  const int node = blockIdx.x >> 1, h = blockIdx.x & 1;
  const int j = node & 15;
  if (j < D) return;  // no passthrough copies
  __shared__ f16 Ph[80 * LDK], Pl[80 * LDK];
  const int tid = threadIdx.x;
  const int prev = node - D;
  const int jp = j - D;
  int Lp = 0;
  if (jp > 0) {
    Lp = 1 << (31 - __clz(jp));
    if (Lp > (D >> 1)) Lp = D >> 1;
  }
  const bool pB = (Lp == 1 || Lp == 4);
  const f16* pMh = (pB ? MhB : MhA) + (size_t)prev * 16384;
  const f16* pMl = (pB ? MlB : MlA) + (size_t)prev * 16384;
  const float* pW = (pB ? WB : WA) + (size_t)prev * 4096;
  // own node: latest level is D/2 -> A for D in {1,4}, B for D in {2,8}
  constexpr bool oB = (D == 2 || D == 8);
  const f16* nMh = (oB ? MhB : MhA) + (size_t)node * 16384;
  const f16* nMl = (oB ? MlB : MlA) + (size_t)node * 16384;
  const float* nW = (oB ? WB : WA) + (size_t)node * 4096;

  load_prev_to_P(pMh, pMl, pW, h, Ph, Pl);
  const int wv = tid >> 6;
  const int mt = (wv == 4) ? (8 + h) : slot2mt(h, wv);
  chain_step<false, 2>(nullptr, nMh, nMl, nW, nullptr, Ph, Pl, wv, mt);
  chain_copyout(Ph, Pl, h, oMh + (size_t)node * 16384,
                oMl + (size_t)node * 16384, oW + (size_t)node * 4096);
}

// ---------------------------------------------------------------------------
// Group-level KS over the 16 group totals (replaces serial kgroup).
// Group node storage overlaid into stale B-set slots: G0 -> slot 16t+0,
// G1 -> slot 16t+2 (j-classes 0 and 2 of set B are never live there).
// L0 (group totals) = chunk set A slot 16t+15. Writes: D=1->G0, 2->G1,
// 4->G0, 8->G1. grid 32, 320 thr.
template <int D>
__global__ __launch_bounds__(320, 3) void gks(const f16* MhA, const f16* MlA,
                                              const float* WA, f16* MhB,
                                              f16* MlB, float* WB) {
  const int g = blockIdx.x >> 1, h = blockIdx.x & 1;
  if (g < D) return;
  __shared__ f16 Ph[80 * LDK], Pl[80 * LDK];
  const int tid = threadIdx.x;
  const int jp = g - D;
  int Lp = 0;
  if (jp > 0) {
    Lp = 1 << (31 - __clz(jp));
    if (Lp > (D >> 1)) Lp = D >> 1;
  }
  const f16 *pMh, *pMl;
  const float* pW;
  if (Lp == 0) {
    const size_t s = (size_t)(16 * jp + 15);
    pMh = MhA + s * 16384; pMl = MlA + s * 16384; pW = WA + s * 4096;
  } else {
    const int off = (Lp == 1 || Lp == 4) ? 0 : 2;  // G0 : G1
    const size_t s = (size_t)(16 * jp + off);
    pMh = MhB + s * 16384; pMl = MlB + s * 16384; pW = WB + s * 4096;
  }
  const f16 *nMh, *nMl;
  const float* nW;
  if (D == 1) {
    const size_t s = (size_t)(16 * g + 15);
    nMh = MhA + s * 16384; nMl = MlA + s * 16384; nW = WA + s * 4096;
  } else {
    constexpr int off = (D == 4) ? 2 : 0;  // own: D=2->G0, D=4->G1, D=8->G0
    const size_t s = (size_t)(16 * g + off);
    nMh = MhB + s * 16384; nMl = MlB + s * 16384; nW = WB + s * 4096;
  }
  constexpr int oOff = (D == 1 || D == 4) ? 0 : 2;
  const size_t so = (size_t)(16 * g + oOff);
  f16* oMh = MhB + so * 16384;
  f16* oMl = MlB + so * 16384;
  float* oW = WB + so * 4096;

  load_prev_to_P(pMh, pMl, pW, h, Ph, Pl);
  const int wv = tid >> 6;
  const int mt = (wv == 4) ? (8 + h) : slot2mt(h, wv);
  chain_step<false, 2>(nullptr, nMh, nMl, nW, nullptr, Ph, Pl, wv, mt);
  chain_copyout(Ph, Pl, h, oMh, oMl, oW);
}

// ---------------------------------------------------------------------------
// K3 h-split: grid 512 (c = bid>>1, h = bid&1), 320 thr, 16 batch rows each.
// entry = W of group-prefix node g-1 (f32); if j>0 apply chunk prefix c-1;
// then replay 4 timesteps writing out.
__global__ __launch_bounds__(320, 3) void k3h(const float* __restrict__ A,
                                              const float* __restrict__ x,
                                              const float* __restrict__ Bv,
                                              const f16* __restrict__ MhA,
                                              const f16* __restrict__ MlA,
                                              const float* __restrict__ WA,
                                              const f16* __restrict__ MhB,
                                              const f16* __restrict__ MlB,
                                              const float* __restrict__ WB,
                                              float* __restrict__ out) {
  __shared__ f16 Sh[16 * LDK], Sl[16 * LDK];
  const int tid = threadIdx.x;
  const int c = blockIdx.x >> 1, h = blockIdx.x & 1;
  const int g = c >> 4, j = c & 15;
  // entry state: group-prefix W of node t = g-1
  // final map: t=0 -> chunk A slot 15; t=1,4..7 -> G0 (16t); else G1 (16t+2)
  const float* Ew = nullptr;
  if (g > 0) {
    const int t = g - 1;
    if (t == 0) Ew = WA + (size_t)15 * 4096;
    else if (t == 1 || (t >= 4 && t <= 7)) Ew = WB + (size_t)(16 * t) * 4096;
    else Ew = WB + (size_t)(16 * t + 2) * 4096;
  }
  for (int tt = tid; tt < 2048; tt += 320) {
    const int row = tt & 15, n = tt >> 4;
    const float v = Ew ? Ew[n * 32 + h * 16 + row] : 0.f;
    const f16 hh = (f16)v;
    Sh[row * LDK + n] = hh;
    Sl[row * LDK + n] = (f16)(v - (float)hh);
  }
  __syncthreads();
  if (j > 0) {
    // chunk-final map on j' = j-1: {0,2,3,8..14} -> A, {1,4..7} -> B
    const int nd = c - 1, jp = j - 1;
    const bool inB = (jp == 1 || (jp >= 4 && jp <= 7));
    const f16* mh = (inB ? MhB : MhA) + (size_t)nd * 16384;
    const f16* ml = (inB ? MlB : MlA) + (size_t)nd * 16384;
    const float* w = (inB ? WB : WA) + (size_t)nd * 4096;
    state_step_h<false, 2>(nullptr, mh, ml, w, nullptr, Sh, Sl, nullptr, h);
  }
#pragma unroll 1
  for (int t4 = 0; t4 < 4; ++t4) {
    const int l = 4 * c + t4;
    state_step_h<true, 1>(A + (size_t)l * 16384, nullptr, nullptr, x + l * 32,
                          Bv + l * 128, Sh, Sl, out + (size_t)l * 4096, h);
  }
}

// ---------------------------------------------------------------------------
extern "C" void kernel_launch(void* const* d_in, const int* in_sizes, int n_in,
                              void* d_out, int out_size, void* d_ws, size_t ws_size,
                              hipStream_t stream) {
  const float* x  = (const float*)d_in[0];  // (1024, 32)
  const float* A  = (const float*)d_in[1];  // (1024, 128, 128) lower-triangular
  const float* Bv = (const float*)d_in[2];  // (1024, 128)
  float* out = (float*)d_out;               // (1024, 32, 128)

  // set A
  f16* MhA = (f16*)d_ws;                    // 256*16384 f16
  f16* MlA = MhA + 256 * 16384;
  float* WA = (float*)(MlA + 256 * 16384);  // 256*4096 f32
  // set B
  f16* MhB = (f16*)(WA + 256 * 4096);
  f16* MlB = MhB + 256 * 16384;
  float* WB = (float*)(MlB + 256 * 16384);  // total ~41.9 MB

  k1_chunks<<<512, 320, 0, stream>>>(A, x, Bv, MhA, MlA, WA);
  ks_np<1><<<512, 320, 0, stream>>>(MhA, MlA, WA, MhB, MlB, WB, MhB, MlB, WB);
  ks_np<2><<<512, 320, 0, stream>>>(MhA, MlA, WA, MhB, MlB, WB, MhA, MlA, WA);
  ks_np<4><<<512, 320, 0, stream>>>(MhA, MlA, WA, MhB, MlB, WB, MhB, MlB, WB);
  ks_np<8><<<512, 320, 0, stream>>>(MhA, MlA, WA, MhB, MlB, WB, MhA, MlA, WA);
  gks<1><<<32, 320, 0, stream>>>(MhA, MlA, WA, MhB, MlB, WB);
  gks<2><<<32, 320, 0, stream>>>(MhA, MlA, WA, MhB, MlB, WB);
  gks<4><<<32, 320, 0, stream>>>(MhA, MlA, WA, MhB, MlB, WB);
  gks<8><<<32, 320, 0, stream>>>(MhA, MlA, WA, MhB, MlB, WB);
  k3h<<<512, 320, 0, stream>>>(A, x, Bv, MhA, MlA, WA, MhB, MlB, WB, out);
}

// Round 2
// 356.817 us; speedup vs baseline: 1.0540x; 1.0540x over previous
//
#include <hip/hip_runtime.h>

// HiPPO-LegS scan — round 8: LDS-staged A operands (latency fix), spill revert.
//  * Revert launch_bounds to plain (320): round-7's (320,3) caused scratch
//    spills (WRITE_SIZE 20.5->32.7 MB) and slowed k1.
//  * k1/k3h: B-operand (A_l triangular slice, rows>=32) staged into LDS via
//    global_load_lds (async, zero VGPR), double-buffered ACROSS chain steps:
//    issue step j+1's stage between step j's two barriers. Rows 0..31 (nt<2)
//    load direct to registers. Bank-conflict fix: chunk index XOR (row&7),
//    applied as inverse-permuted GLOBAL source + mirrored LDS read (rule #21).
//  * Keep round-7 structure: passthrough-free KS, group-KS, h-split k3.
// Pipeline: k1(512) -> ks_np<1,2,4,8>(512) -> gks<1,2,4,8>(32) -> k3h(512).

#define LDK 136  // f16 k-stride of LDS state rows

using f16 = _Float16;
typedef __attribute__((ext_vector_type(8))) f16 f16x8;
typedef __attribute__((ext_vector_type(4))) float f32x4;

__device__ __forceinline__ f32x4 mfma3(f16x8 ah, f16x8 al, f16x8 bh, f16x8 bl,
                                       f32x4 c) {
  c = __builtin_amdgcn_mfma_f32_16x16x32_f16(ah, bh, c, 0, 0, 0);
  c = __builtin_amdgcn_mfma_f32_16x16x32_f16(ah, bl, c, 0, 0, 0);
  c = __builtin_amdgcn_mfma_f32_16x16x32_f16(al, bh, c, 0, 0, 0);
  return c;
}

__device__ __forceinline__ void split8(const float* v, f16x8& h, f16x8& l) {
#pragma unroll
  for (int j = 0; j < 8; ++j) {
    const float x = v[j];
    const f16 hh = (f16)x;
    h[j] = hh;
    l[j] = (f16)(x - (float)hh);
  }
}

// global m-tile owned by (h, slot): h=0 -> {0,7,1,6}, h=1 -> {2,5,3,4}
__device__ __forceinline__ int slot2mt(int h, int slot) {
  if (h == 0) return (slot & 1) ? 7 - (slot >> 1) : (slot >> 1);
  return (slot & 1) ? 5 - (slot >> 1) : 2 + (slot >> 1);
}

// ---------------------------------------------------------------------------
// Staged-A layout (f32, LDS, 9216 floats = 36 KB): triangular slice rows>=32,
// packed per k-tile: kt0 rows 32..127, kt1 rows 32..127, kt2 rows 64..127,
// kt3 rows 96..127; each row-slice = 32 f32 = 8 chunks of 16B.
// chunk counts {768,768,512,256}, f32 bases {0,3072,6144,8192}.
// Swizzle: within a row, chunk c holds global chunk (c ^ (rp&7)).

__device__ __forceinline__ void gload_lds16(const float* g, float* l) {
  __builtin_amdgcn_global_load_lds(
      (const __attribute__((address_space(1))) unsigned int*)g,
      (__attribute__((address_space(3))) unsigned int*)l, 16, 0, 0);
}

// per-thread step-invariant source offsets (f32 units into A_l)
__device__ __forceinline__ void compute_soff(int tid, int (&soff)[8]) {
#pragma unroll
  for (int it = 0; it < 8; ++it) {
    const int m = tid + it * 320;  // LDS chunk index
    if (m < 2304) {
      const int kt = (m >= 768) + (m >= 1536) + (m >= 2048);
      const int local = m - ((kt >= 1) * 768 + (kt >= 2) * 768 + (kt >= 3) * 512);
      const int rp = local >> 3, c = local & 7;
      const int r = rp + 32 + (kt >= 2) * 32 + (kt >= 3) * 32;
      soff[it] = r * 128 + kt * 32 + ((c ^ (rp & 7)) << 2);
    } else {
      soff[it] = 0;
    }
  }
}

__device__ __forceinline__ void issue_A(const float* __restrict__ Al,
                                        float* __restrict__ Ast,
                                        const int (&soff)[8], int tid) {
#pragma unroll
  for (int it = 0; it < 8; ++it) {
    if (it < 7 || tid < 64)  // 2304 = 7*320 + 64 (wave 0 only on last iter)
      gload_lds16(Al + soff[it], Ast + (tid + it * 320) * 4);
  }
}

// staged B-fragment read (nt>=2): two swizzled 16B LDS reads + split
__device__ __forceinline__ void read_staged(const float* __restrict__ Ast,
                                            int nt, int kt, int lr, int q,
                                            f16x8& ch, f16x8& cl) {
  const int rp = nt * 16 + lr - (32 + (kt >= 2) * 32 + (kt >= 3) * 32);
  const float* pb =
      Ast + ((kt >= 1) * 3072 + (kt >= 2) * 3072 + (kt >= 3) * 2048) + rp * 32;
  float raw[8];
  *(float4*)&raw[0] = *(const float4*)(pb + (((2 * q + 0) ^ (rp & 7)) << 2));
  *(float4*)&raw[4] = *(const float4*)(pb + (((2 * q + 1) ^ (rp & 7)) << 2));
  split8(raw, ch, cl);
}

// ---------------------------------------------------------------------------
// chain_step (b16 global B path) — used by ks_np / gks. Unchanged math.
// EXTRA==2: w-rows += w_add f32 [n][32b] (aux0)
template <int EXTRA>
__device__ __forceinline__ void chain_step_b16(const f16* __restrict__ Bh16,
                                               const f16* __restrict__ Bl16,
                                               const float* __restrict__ aux0,
                                               f16* __restrict__ Ph,
                                               f16* __restrict__ Pl,
                                               int wv, int mt) {
  const int lane = threadIdx.x & 63;
  const int lr = lane & 15, q = lane >> 4;
  const bool wrow = (mt >= 8);
  const int ktA0 = wrow ? 0 : (mt >> 1);
  f16x8 ah[4], al[4];
#pragma unroll
  for (int kt = 0; kt < 4; ++kt) {
    if (kt >= ktA0) {
      const int off = (wv * 16 + lr) * LDK + kt * 32 + q * 8;
      ah[kt] = *(const f16x8*)(Ph + off);
      al[kt] = *(const f16x8*)(Pl + off);
    }
  }
  f32x4 acc[8];
#pragma unroll
  for (int nt = 0; nt < 8; ++nt) acc[nt] = (f32x4){0.f, 0.f, 0.f, 0.f};

  f16x8 b16h[2][4], b16l[2][4];
  auto loadB = [&](int nt, int s) {
#pragma unroll
    for (int kt = 0; kt < 4; ++kt) {
      if (kt >= ktA0 && kt <= (nt >> 1)) {
        const int o = (nt * 16 + lr) * 128 + kt * 32 + q * 8;
        b16h[s][kt] = *(const f16x8*)(Bh16 + o);
        b16l[s][kt] = *(const f16x8*)(Bl16 + o);
      }
    }
  };

  if (wrow || mt == 0) loadB(0, 0);
#pragma unroll
  for (int nt = 0; nt < 8; ++nt) {
    const int cur = nt & 1;
    if (nt < 7 && (wrow || (nt + 1) >= mt)) loadB(nt + 1, cur ^ 1);
    if (wrow || nt >= mt) {
#pragma unroll
      for (int kt = 0; kt < 4; ++kt)
        if (kt >= ktA0 && kt <= (nt >> 1))
          acc[nt] = mfma3(ah[kt], al[kt], b16h[cur][kt], b16l[cur][kt], acc[nt]);
    }
  }
  __syncthreads();
#pragma unroll
  for (int nt = 0; nt < 8; ++nt) {
    if (!(wrow || nt >= mt)) continue;
    float v[4] = {acc[nt][0], acc[nt][1], acc[nt][2], acc[nt][3]};
    if (wrow) {
      const int b0 = (mt - 8) * 16 + q * 4;
      if (EXTRA == 2) {
        const float4 w4 = *(const float4*)(aux0 + (nt * 16 + lr) * 32 + b0);
        v[0] += w4.x; v[1] += w4.y; v[2] += w4.z; v[3] += w4.w;
      }
    }
#pragma unroll
    for (int r = 0; r < 4; ++r) {
      const int o = (wv * 16 + q * 4 + r) * LDK + nt * 16 + lr;
      const f16 hh = (f16)v[r];
      Ph[o] = hh;
      Pl[o] = (f16)(v[r] - (float)hh);
    }
  }
  __syncthreads();
}

// ---------------------------------------------------------------------------
// chain_step_k1: B operand from staged LDS (nt>=2) + direct regs (nt<2).
// Issues next step's A staging between the two barriers. EXTRA==1 semantics.
__device__ __forceinline__ void chain_step_k1(const float* __restrict__ Acur,
                                              const float* __restrict__ Anext,
                                              const float* __restrict__ x32,
                                              const float* __restrict__ Bvl,
                                              f16* __restrict__ Ph,
                                              f16* __restrict__ Pl,
                                              float* __restrict__ Ast,
                                              const int (&soff)[8],
                                              int wv, int mt) {
  const int tid = threadIdx.x;
  const int lane = tid & 63, lr = lane & 15, q = lane >> 4;
  const bool wrow = (mt >= 8);
  const int ktA0 = wrow ? 0 : (mt >> 1);
  f16x8 ah[4], al[4];
#pragma unroll
  for (int kt = 0; kt < 4; ++kt) {
    if (kt >= ktA0) {
      const int off = (wv * 16 + lr) * LDK + kt * 32 + q * 8;
      ah[kt] = *(const f16x8*)(Ph + off);
      al[kt] = *(const f16x8*)(Pl + off);
    }
  }
  // direct rows 0..31 (kt0 only), issued early
  const bool need0 = wrow || mt == 0;
  const bool need1 = wrow || mt <= 1;
  float dir0[8], dir1[8];
  if (need0) {
    const float* p = Acur + lr * 128 + q * 8;
    *(float4*)&dir0[0] = *(const float4*)p;
    *(float4*)&dir0[4] = *(const float4*)(p + 4);
  }
  if (need1) {
    const float* p = Acur + (16 + lr) * 128 + q * 8;
    *(float4*)&dir1[0] = *(const float4*)p;
    *(float4*)&dir1[4] = *(const float4*)(p + 4);
  }
  f32x4 acc[8];
#pragma unroll
  for (int nt = 0; nt < 8; ++nt) acc[nt] = (f32x4){0.f, 0.f, 0.f, 0.f};
#pragma unroll
  for (int nt = 2; nt < 8; ++nt) {
    if (wrow || nt >= mt) {
#pragma unroll
      for (int kt = 0; kt < 4; ++kt) {
        if (kt >= ktA0 && kt <= (nt >> 1)) {
          f16x8 ch, cl;
          read_staged(Ast, nt, kt, lr, q, ch, cl);
          acc[nt] = mfma3(ah[kt], al[kt], ch, cl, acc[nt]);
        }
      }
    }
  }
  if (need0) {
    f16x8 ch, cl;
    split8(dir0, ch, cl);
    acc[0] = mfma3(ah[0], al[0], ch, cl, acc[0]);
  }
  if (need1) {
    f16x8 ch, cl;
    split8(dir1, ch, cl);
    acc[1] = mfma3(ah[0], al[0], ch, cl, acc[1]);
  }
  __syncthreads();  // all Ast reads + state reads complete
  if (Anext) issue_A(Anext, Ast, soff, tid);  // async overwrite, drained at next barrier
#pragma unroll
  for (int nt = 0; nt < 8; ++nt) {
    if (!(wrow || nt >= mt)) continue;
    float v[4] = {acc[nt][0], acc[nt][1], acc[nt][2], acc[nt][3]};
    if (wrow) {
      const int b0 = (mt - 8) * 16 + q * 4;
      const float4 x4 = *(const float4*)(x32 + b0);
      const float bn = Bvl[nt * 16 + lr];
      v[0] += bn * x4.x; v[1] += bn * x4.y; v[2] += bn * x4.z; v[3] += bn * x4.w;
    }
#pragma unroll
    for (int r = 0; r < 4; ++r) {
      const int o = (wv * 16 + q * 4 + r) * LDK + nt * 16 + lr;
      const f16 hh = (f16)v[r];
      Ph[o] = hh;
      Pl[o] = (f16)(v[r] - (float)hh);
    }
  }
  __syncthreads();
}

// copy P' (= result^T in LDS) out as PLAIN M (f16 hi/lo) + w (f32 [n][32])
__device__ __forceinline__ void chain_copyout(const f16* __restrict__ Ph,
                                              const f16* __restrict__ Pl, int h,
                                              f16* __restrict__ oMh,
                                              f16* __restrict__ oMl,
                                              float* __restrict__ oW) {
  const int tid = threadIdx.x;
  for (int t = tid; t < 1024; t += 320) {
    const int i = t >> 3;
    const int slot = (t >> 1) & 3;
    const int half = t & 1;
    const int mtg = slot2mt(h, slot);
    f16x8 hv, lv;
#pragma unroll
    for (int e = 0; e < 8; ++e) {
      hv[e] = Ph[(slot * 16 + half * 8 + e) * LDK + i];
      lv[e] = Pl[(slot * 16 + half * 8 + e) * LDK + i];
    }
    *(f16x8*)(oMh + i * 128 + mtg * 16 + half * 8) = hv;
    *(f16x8*)(oMl + i * 128 + mtg * 16 + half * 8) = lv;
  }
  for (int t = tid; t < 512; t += 320) {
    const int n = t >> 2, b4 = (t & 3) * 4;
    float4 o;
    float* po = (float*)&o;
#pragma unroll
    for (int e = 0; e < 4; ++e)
      po[e] = (float)Ph[(64 + b4 + e) * LDK + n] + (float)Pl[(64 + b4 + e) * LDK + n];
    *(float4*)(oW + n * 32 + h * 16 + b4) = o;
  }
}

// P'-init: load prev node's plain M + W into LDS (transposed). Trailing barrier.
__device__ __forceinline__ void load_prev_to_P(const f16* pMh, const f16* pMl,
                                               const float* pW, int h,
                                               f16* Ph, f16* Pl) {
  const int tid = threadIdx.x;
  for (int t = tid; t < 1024; t += 320) {
    const int k = t >> 3, u = t & 7;
    const int slot = u >> 1, half = u & 1;
    const int mtg = slot2mt(h, slot);
    const f16x8 hv = *(const f16x8*)(pMh + k * 128 + mtg * 16 + half * 8);
    const f16x8 lv = *(const f16x8*)(pMl + k * 128 + mtg * 16 + half * 8);
#pragma unroll
    for (int e = 0; e < 8; ++e) {
      Ph[(slot * 16 + half * 8 + e) * LDK + k] = hv[e];
      Pl[(slot * 16 + half * 8 + e) * LDK + k] = lv[e];
    }
  }
  for (int t = tid; t < 2048; t += 320) {
    const int n = t >> 4, b = t & 15;
    const float wv0 = pW[n * 32 + h * 16 + b];
    const f16 hh = (f16)wv0;
    Ph[(64 + b) * LDK + n] = hh;
    Pl[(64 + b) * LDK + n] = (f16)(wv0 - (float)hh);
  }
  __syncthreads();
}

// ---------------------------------------------------------------------------
// state_step_h (b16 path): 16-row state <- state * B^T (+w add). 320 threads;
// waves 0..3 compute, wave 4 barriers only. Used for k3h prefix-apply.
__device__ __forceinline__ void state_step_h_b16(const f16* __restrict__ Bh16,
                                                 const f16* __restrict__ Bl16,
                                                 const float* __restrict__ aux0,
                                                 f16* __restrict__ Sh,
                                                 f16* __restrict__ Sl, int h) {
  const int tid = threadIdx.x;
  const int wv4 = tid >> 6;
  const bool act = (wv4 < 4);
  const int wv = wv4 & 3;
  const int lane = tid & 63, lr = lane & 15, q = lane >> 4;
  const int nts[2] = {wv, 7 - wv};
  const int ktAmax = (7 - wv) >> 1;
  f16x8 ah[4], al[4];
  f16x8 bh[2][4], bl[2][4];
  f32x4 acc[2];
  if (act) {
#pragma unroll
    for (int kt = 0; kt < 4; ++kt)
      if (kt <= ktAmax) {
        const int off = lr * LDK + kt * 32 + q * 8;
        ah[kt] = *(const f16x8*)(Sh + off);
        al[kt] = *(const f16x8*)(Sl + off);
      }
#pragma unroll
    for (int ni = 0; ni < 2; ++ni) {
      const int nt = nts[ni];
#pragma unroll
      for (int kt = 0; kt < 4; ++kt)
        if (kt <= (nt >> 1)) {
          const int o = (nt * 16 + lr) * 128 + kt * 32 + q * 8;
          bh[ni][kt] = *(const f16x8*)(Bh16 + o);
          bl[ni][kt] = *(const f16x8*)(Bl16 + o);
        }
    }
#pragma unroll
    for (int ni = 0; ni < 2; ++ni) acc[ni] = (f32x4){0.f, 0.f, 0.f, 0.f};
#pragma unroll
    for (int ni = 0; ni < 2; ++ni) {
      const int nt = nts[ni];
#pragma unroll
      for (int kt = 0; kt < 4; ++kt)
        if (kt <= (nt >> 1))
          acc[ni] = mfma3(ah[kt], al[kt], bh[ni][kt], bl[ni][kt], acc[ni]);
    }
  }
  __syncthreads();
  if (act) {
#pragma unroll
    for (int ni = 0; ni < 2; ++ni) {
      const int nt = nts[ni];
      float v[4] = {acc[ni][0], acc[ni][1], acc[ni][2], acc[ni][3]};
      const int bq = q * 4;
      const float4 w4 = *(const float4*)(aux0 + (nt * 16 + lr) * 32 + h * 16 + bq);
      v[0] += w4.x; v[1] += w4.y; v[2] += w4.z; v[3] += w4.w;
#pragma unroll
      for (int r = 0; r < 4; ++r) {
        const int o = (bq + r) * LDK + nt * 16 + lr;
        const f16 hh = (f16)v[r];
        Sh[o] = hh;
        Sl[o] = (f16)(v[r] - (float)hh);
      }
    }
  }
  __syncthreads();
}

// state_step_h_staged: B from staged LDS (nt>=2) + direct regs (nt<2 on wv<2).
// Issues next step's A staging between barriers. EXTRA==1 semantics + out.
__device__ __forceinline__ void state_step_h_staged(
    const float* __restrict__ Acur, const float* __restrict__ Anext,
    const float* __restrict__ x32, const float* __restrict__ Bvl,
    f16* __restrict__ Sh, f16* __restrict__ Sl, float* __restrict__ outp,
    int h, float* __restrict__ Ast, const int (&soff)[8]) {
  const int tid = threadIdx.x;
  const int wv4 = tid >> 6;
  const bool act = (wv4 < 4);
  const int wv = wv4 & 3;
  const int lane = tid & 63, lr = lane & 15, q = lane >> 4;
  const int ntL = wv, ntH = 7 - wv;
  f32x4 accL = (f32x4){0.f, 0.f, 0.f, 0.f}, accH = accL;
  if (act) {
    const int ktAmax = ntH >> 1;
    f16x8 ah[4], al[4];
#pragma unroll
    for (int kt = 0; kt < 4; ++kt)
      if (kt <= ktAmax) {
        const int off = lr * LDK + kt * 32 + q * 8;
        ah[kt] = *(const f16x8*)(Sh + off);
        al[kt] = *(const f16x8*)(Sl + off);
      }
    float dir[8];
    if (wv < 2) {  // ntL in {0,1}: direct kt0 rows
      const float* p = Acur + (ntL * 16 + lr) * 128 + q * 8;
      *(float4*)&dir[0] = *(const float4*)p;
      *(float4*)&dir[4] = *(const float4*)(p + 4);
    }
    // staged high nt (4..7)
#pragma unroll
    for (int kt = 0; kt < 4; ++kt) {
      if (kt <= (ntH >> 1)) {
        f16x8 ch, cl;
        read_staged(Ast, ntH, kt, lr, q, ch, cl);
        accH = mfma3(ah[kt], al[kt], ch, cl, accH);
      }
    }
    if (wv >= 2) {  // ntL in {2,3}: staged
#pragma unroll
      for (int kt = 0; kt < 4; ++kt) {
        if (kt <= (ntL >> 1)) {
          f16x8 ch, cl;
          read_staged(Ast, ntL, kt, lr, q, ch, cl);
          accL = mfma3(ah[kt], al[kt], ch, cl, accL);
        }
      }
    } else {
      f16x8 ch, cl;
      split8(dir, ch, cl);
      accL = mfma3(ah[0], al[0], ch, cl, accL);
    }
  }
  __syncthreads();
  if (Anext) issue_A(Anext, Ast, soff, tid);
  if (act) {
#pragma unroll
    for (int ni = 0; ni < 2; ++ni) {
      const int nt = (ni == 0) ? ntL : ntH;
      const f32x4 a = (ni == 0) ? accL : accH;
      float v[4] = {a[0], a[1], a[2], a[3]};
      const int bq = q * 4;
      const float4 x4 = *(const float4*)(x32 + h * 16 + bq);
      const float bn = Bvl[nt * 16 + lr];
      v[0] += bn * x4.x; v[1] += bn * x4.y; v[2] += bn * x4.z; v[3] += bn * x4.w;
      if (outp) {
#pragma unroll
        for (int r = 0; r < 4; ++r)
          outp[(h * 16 + bq + r) * 128 + nt * 16 + lr] = v[r];
      }
#pragma unroll
      for (int r = 0; r < 4; ++r) {
        const int o = (bq + r) * LDK + nt * 16 + lr;
        const f16 hh = (f16)v[r];
        Sh[o] = hh;
        Sl[o] = (f16)(v[r] - (float)hh);
      }
    }
  }
  __syncthreads();
}

// ---------------------------------------------------------------------------
// K1: chunk units. grid 512 (c = bid>>1, h = bid&1), 320 threads. writes set A.
__global__ __launch_bounds__(320) void k1_chunks(const float* __restrict__ A,
                                                 const float* __restrict__ x,
                                                 const float* __restrict__ Bv,
                                                 f16* __restrict__ Mh,
                                                 f16* __restrict__ Ml,
                                                 float* __restrict__ Wf) {
  __shared__ f16 Ph[80 * LDK], Pl[80 * LDK];
  __shared__ float Ast[9216];
  const int tid = threadIdx.x;
  const int c = blockIdx.x >> 1, h = blockIdx.x & 1;
  const int l0 = 4 * c;
  int soff[8];
  compute_soff(tid, soff);
  issue_A(A + (size_t)(l0 + 1) * 16384, Ast, soff, tid);  // stage step 1 early
  const float* A0 = A + (size_t)l0 * 16384;
  for (int t = tid; t < 2048; t += 320) {
    const int k = t >> 4, u = t & 15;
    const int slot = u >> 2, fo = (u & 3) * 4;
    const int mtg = slot2mt(h, slot);
    const float4 v = *(const float4*)(A0 + k * 128 + mtg * 16 + fo);
    const float vv[4] = {v.x, v.y, v.z, v.w};
#pragma unroll
    for (int e = 0; e < 4; ++e) {
      const f16 hh = (f16)vv[e];
      Ph[(slot * 16 + fo + e) * LDK + k] = hh;
      Pl[(slot * 16 + fo + e) * LDK + k] = (f16)(vv[e] - (float)hh);
    }
  }
  for (int t = tid; t < 512; t += 320) {
    const int b = t >> 5, n4 = (t & 31) * 4;
    const float xb = x[l0 * 32 + h * 16 + b];
#pragma unroll
    for (int e = 0; e < 4; ++e) {
      const float u = xb * Bv[l0 * 128 + n4 + e];
      const f16 hh = (f16)u;
      Ph[(64 + b) * LDK + n4 + e] = hh;
      Pl[(64 + b) * LDK + n4 + e] = (f16)(u - (float)hh);
    }
  }
  __syncthreads();  // drains vmcnt: staged A for step 1 ready
  const int wv = tid >> 6;
  const int mt = (wv == 4) ? (8 + h) : slot2mt(h, wv);
  chain_step_k1(A + (size_t)(l0 + 1) * 16384, A + (size_t)(l0 + 2) * 16384,
                x + (l0 + 1) * 32, Bv + (l0 + 1) * 128, Ph, Pl, Ast, soff, wv, mt);
  chain_step_k1(A + (size_t)(l0 + 2) * 16384, A + (size_t)(l0 + 3) * 16384,
                x + (l0 + 2) * 32, Bv + (l0 + 2) * 128, Ph, Pl, Ast, soff, wv, mt);
  chain_step_k1(A + (size_t)(l0 + 3) * 16384, nullptr,
                x + (l0 + 3) * 32, Bv + (l0 + 3) * 128, Ph, Pl, Ast, soff, wv, mt);
  chain_copyout(Ph, Pl, h, Mh + (size_t)c * 16384, Ml + (size_t)c * 16384,
                Wf + (size_t)c * 4096);
}

// ---------------------------------------------------------------------------
// Passthrough-free Kogge-Stone level D over within-group (16) prefixes.
// grid 512, 320 thr; blocks with j<D exit. Source buffer per node class:
// L = min(pow2floor(j'), D/2); L in {0,2,8} -> set A, {1,4} -> set B.
template <int D>
__global__ __launch_bounds__(320) void ks_np(const f16* MhA, const f16* MlA,
                                             const float* WA, const f16* MhB,
                                             const f16* MlB, const float* WB,
                                             f16* oMh, f16* oMl, float* oW) {
  const int node = blockIdx.x >> 1, h = blockIdx.x & 1;
  const int j = node & 15;
  if (j < D) return;  // no passthrough copies
  __shared__ f16 Ph[80 * LDK], Pl[80 * LDK];
  const int tid = threadIdx.x;
  const int prev = node - D;
  const int jp = j - D;
  int Lp = 0;
  if (jp > 0) {
    Lp = 1 << (31 - __clz(jp));
    if (Lp > (D >> 1)) Lp = D >> 1;
  }
  const bool pB = (Lp == 1 || Lp == 4);
  const f16* pMh = (pB ? MhB : MhA) + (size_t)prev * 16384;
  const f16* pMl = (pB ? MlB : MlA) + (size_t)prev * 16384;
  const float* pW = (pB ? WB : WA) + (size_t)prev * 4096;
  // own node: latest level is D/2 -> A for D in {1,4}, B for D in {2,8}
  constexpr bool oB = (D == 2 || D == 8);
  const f16* nMh = (oB ? MhB : MhA) + (size_t)node * 16384;
  const f16* nMl = (oB ? MlB : MlA) + (size_t)node * 16384;
  const float* nW = (oB ? WB : WA) + (size_t)node * 4096;

  load_prev_to_P(pMh, pMl, pW, h, Ph, Pl);
  const int wv = tid >> 6;
  const int mt = (wv == 4) ? (8 + h) : slot2mt(h, wv);
  chain_step_b16<2>(nMh, nMl, nW, Ph, Pl, wv, mt);
  chain_copyout(Ph, Pl, h, oMh + (size_t)node * 16384,
                oMl + (size_t)node * 16384, oW + (size_t)node * 4096);
}

// ---------------------------------------------------------------------------
// Group-level KS over the 16 group totals. Group node storage overlaid into
// stale B-set slots: G0 -> slot 16t+0, G1 -> slot 16t+2. L0 (group totals) =
// chunk set A slot 16t+15. Writes: D=1->G0, 2->G1, 4->G0, 8->G1. grid 32.
template <int D>
__global__ __launch_bounds__(320) void gks(const f16* MhA, const f16* MlA,
                                           const float* WA, f16* MhB,
                                           f16* MlB, float* WB) {
  const int g = blockIdx.x >> 1, h = blockIdx.x & 1;
  if (g < D) return;
  __shared__ f16 Ph[80 * LDK], Pl[80 * LDK];
  const int tid = threadIdx.x;
  const int jp = g - D;
  int Lp = 0;
  if (jp > 0) {
    Lp = 1 << (31 - __clz(jp));
    if (Lp > (D >> 1)) Lp = D >> 1;
  }
  const f16 *pMh, *pMl;
  const float* pW;
  if (Lp == 0) {
    const size_t s = (size_t)(16 * jp + 15);
    pMh = MhA + s * 16384; pMl = MlA + s * 16384; pW = WA + s * 4096;
  } else {
    const int off = (Lp == 1 || Lp == 4) ? 0 : 2;  // G0 : G1
    const size_t s = (size_t)(16 * jp + off);
    pMh = MhB + s * 16384; pMl = MlB + s * 16384; pW = WB + s * 4096;
  }
  const f16 *nMh, *nMl;
  const float* nW;
  if (D == 1) {
    const size_t s = (size_t)(16 * g + 15);
    nMh = MhA + s * 16384; nMl = MlA + s * 16384; nW = WA + s * 4096;
  } else {
    constexpr int off = (D == 4) ? 2 : 0;  // own: D=2->G0, D=4->G1, D=8->G0
    const size_t s = (size_t)(16 * g + off);
    nMh = MhB + s * 16384; nMl = MlB + s * 16384; nW = WB + s * 4096;
  }
  constexpr int oOff = (D == 1 || D == 4) ? 0 : 2;
  const size_t so = (size_t)(16 * g + oOff);
  f16* oMh = MhB + so * 16384;
  f16* oMl = MlB + so * 16384;
  float* oW = WB + so * 4096;

  load_prev_to_P(pMh, pMl, pW, h, Ph, Pl);
  const int wv = tid >> 6;
  const int mt = (wv == 4) ? (8 + h) : slot2mt(h, wv);
  chain_step_b16<2>(nMh, nMl, nW, Ph, Pl, wv, mt);
  chain_copyout(Ph, Pl, h, oMh, oMl, oW);
}

// ---------------------------------------------------------------------------
// K3 h-split: grid 512 (c = bid>>1, h = bid&1), 320 thr, 16 batch rows each.
// entry = W of group-prefix node g-1 (f32); if j>0 apply chunk prefix c-1;
// then replay 4 timesteps (staged-A pipeline) writing out.
__global__ __launch_bounds__(320) void k3h(const float* __restrict__ A,
                                           const float* __restrict__ x,
                                           const float* __restrict__ Bv,
                                           const f16* __restrict__ MhA,
                                           const f16* __restrict__ MlA,
                                           const float* __restrict__ WA,
                                           const f16* __restrict__ MhB,
                                           const f16* __restrict__ MlB,
                                           const float* __restrict__ WB,
                                           float* __restrict__ out) {
  __shared__ f16 Sh[16 * LDK], Sl[16 * LDK];
  __shared__ float Ast[9216];
  const int tid = threadIdx.x;
  const int c = blockIdx.x >> 1, h = blockIdx.x & 1;
  const int g = c >> 4, j = c & 15;
  int soff[8];
  compute_soff(tid, soff);
  issue_A(A + (size_t)(4 * c) * 16384, Ast, soff, tid);  // stage t4=0 early
  // entry state: group-prefix W of node t = g-1
  // final map: t=0 -> chunk A slot 15; t=1,4..7 -> G0 (16t); else G1 (16t+2)
  const float* Ew = nullptr;
  if (g > 0) {
    const int t = g - 1;
    if (t == 0) Ew = WA + (size_t)15 * 4096;
    else if (t == 1 || (t >= 4 && t <= 7)) Ew = WB + (size_t)(16 * t) * 4096;
    else Ew = WB + (size_t)(16 * t + 2) * 4096;
  }
  for (int tt = tid; tt < 2048; tt += 320) {
    const int row = tt & 15, n = tt >> 4;
    const float v = Ew ? Ew[n * 32 + h * 16 + row] : 0.f;
    const f16 hh = (f16)v;
    Sh[row * LDK + n] = hh;
    Sl[row * LDK + n] = (f16)(v - (float)hh);
  }
  __syncthreads();  // drains vmcnt: staged A for t4=0 ready
  if (j > 0) {
    // chunk-final map on j' = j-1: {0,2,3,8..14} -> A, {1,4..7} -> B
    const int nd = c - 1, jp = j - 1;
    const bool inB = (jp == 1 || (jp >= 4 && jp <= 7));
    const f16* mh = (inB ? MhB : MhA) + (size_t)nd * 16384;
    const f16* ml = (inB ? MlB : MlA) + (size_t)nd * 16384;
    const float* w = (inB ? WB : WA) + (size_t)nd * 4096;
    state_step_h_b16(mh, ml, w, Sh, Sl, h);
  }
#pragma unroll 1
  for (int t4 = 0; t4 < 4; ++t4) {
    const int l = 4 * c + t4;
    const float* Anext = (t4 < 3) ? A + (size_t)(l + 1) * 16384 : nullptr;
    state_step_h_staged(A + (size_t)l * 16384, Anext, x + l * 32, Bv + l * 128,
                        Sh, Sl, out + (size_t)l * 4096, h, Ast, soff);
  }
}

// ---------------------------------------------------------------------------
extern "C" void kernel_launch(void* const* d_in, const int* in_sizes, int n_in,
                              void* d_out, int out_size, void* d_ws, size_t ws_size,
                              hipStream_t stream) {
  const float* x  = (const float*)d_in[0];  // (1024, 32)
  const float* A  = (const float*)d_in[1];  // (1024, 128, 128) lower-triangular
  const float* Bv = (const float*)d_in[2];  // (1024, 128)
  float* out = (float*)d_out;               // (1024, 32, 128)

  // set A
  f16* MhA = (f16*)d_ws;                    // 256*16384 f16
  f16* MlA = MhA + 256 * 16384;
  float* WA = (float*)(MlA + 256 * 16384);  // 256*4096 f32
  // set B
  f16* MhB = (f16*)(WA + 256 * 4096);
  f16* MlB = MhB + 256 * 16384;
  float* WB = (float*)(MlB + 256 * 16384);  // total ~41.9 MB

  k1_chunks<<<512, 320, 0, stream>>>(A, x, Bv, MhA, MlA, WA);
  ks_np<1><<<512, 320, 0, stream>>>(MhA, MlA, WA, MhB, MlB, WB, MhB, MlB, WB);
  ks_np<2><<<512, 320, 0, stream>>>(MhA, MlA, WA, MhB, MlB, WB, MhA, MlA, WA);
  ks_np<4><<<512, 320, 0, stream>>>(MhA, MlA, WA, MhB, MlB, WB, MhB, MlB, WB);
  ks_np<8><<<512, 320, 0, stream>>>(MhA, MlA, WA, MhB, MlB, WB, MhA, MlA, WA);
  gks<1><<<32, 320, 0, stream>>>(MhA, MlA, WA, MhB, MlB, WB);
  gks<2><<<32, 320, 0, stream>>>(MhA, MlA, WA, MhB, MlB, WB);
  gks<4><<<32, 320, 0, stream>>>(MhA, MlA, WA, MhB, MlB, WB);
  gks<8><<<32, 320, 0, stream>>>(MhA, MlA, WA, MhB, MlB, WB);
  k3h<<<512, 320, 0, stream>>>(A, x, Bv, MhA, MlA, WA, MhB, MlB, WB, out);
}

// Round 3
// 311.119 us; speedup vs baseline: 1.2088x; 1.1469x over previous
//
#include <hip/hip_runtime.h>

// HiPPO-LegS scan — round 9: kill the gks chain + triangular traffic gating.
//  * gks<1,2,4,8> (4 launches of 128x128 matrix products; only the W part was
//    ever consumed) -> ONE gscan kernel (32 blocks): serial Horner state scan
//    over group totals via state_step_h_b16 (round-6 kgroup pattern, h-split),
//    writing f32 entry states Ef[16][4096] (g=0 = zeros).
//  * Triangular gating: prefix matrices are lower-tri in storage coords
//    (M[i][y] nonzero iff y>>5 <= i>>5, matching all readers' 32-tile
//    granularity). Skip 37.5% of copyout stores / load_prev loads / k1 A0
//    loads; skipped global bytes stay garbage, readers gated or zero-fill.
//  * k3h: entry = Ef[g] unconditionally (no source map).
// Pipeline: k1(512) -> ks_np<1,2,4,8>(512) -> gscan(32) -> k3h(512). 7 launches.

#define LDK 136  // f16 k-stride of LDS state rows

using f16 = _Float16;
typedef __attribute__((ext_vector_type(8))) f16 f16x8;
typedef __attribute__((ext_vector_type(4))) float f32x4;

__device__ __forceinline__ f32x4 mfma3(f16x8 ah, f16x8 al, f16x8 bh, f16x8 bl,
                                       f32x4 c) {
  c = __builtin_amdgcn_mfma_f32_16x16x32_f16(ah, bh, c, 0, 0, 0);
  c = __builtin_amdgcn_mfma_f32_16x16x32_f16(ah, bl, c, 0, 0, 0);
  c = __builtin_amdgcn_mfma_f32_16x16x32_f16(al, bh, c, 0, 0, 0);
  return c;
}

__device__ __forceinline__ void split8(const float* v, f16x8& h, f16x8& l) {
#pragma unroll
  for (int j = 0; j < 8; ++j) {
    const float x = v[j];
    const f16 hh = (f16)x;
    h[j] = hh;
    l[j] = (f16)(x - (float)hh);
  }
}

// global m-tile owned by (h, slot): h=0 -> {0,7,1,6}, h=1 -> {2,5,3,4}
__device__ __forceinline__ int slot2mt(int h, int slot) {
  if (h == 0) return (slot & 1) ? 7 - (slot >> 1) : (slot >> 1);
  return (slot & 1) ? 5 - (slot >> 1) : 2 + (slot >> 1);
}

// ---------------------------------------------------------------------------
// Staged-A layout (f32, LDS, 9216 floats = 36 KB): triangular slice rows>=32,
// packed per k-tile: kt0 rows 32..127, kt1 rows 32..127, kt2 rows 64..127,
// kt3 rows 96..127; each row-slice = 32 f32 = 8 chunks of 16B.
// Swizzle: within a row, chunk c holds global chunk (c ^ (rp&7)).

__device__ __forceinline__ void gload_lds16(const float* g, float* l) {
  __builtin_amdgcn_global_load_lds(
      (const __attribute__((address_space(1))) unsigned int*)g,
      (__attribute__((address_space(3))) unsigned int*)l, 16, 0, 0);
}

// per-thread step-invariant source offsets (f32 units into A_l)
__device__ __forceinline__ void compute_soff(int tid, int (&soff)[8]) {
#pragma unroll
  for (int it = 0; it < 8; ++it) {
    const int m = tid + it * 320;  // LDS chunk index
    if (m < 2304) {
      const int kt = (m >= 768) + (m >= 1536) + (m >= 2048);
      const int local = m - ((kt >= 1) * 768 + (kt >= 2) * 768 + (kt >= 3) * 512);
      const int rp = local >> 3, c = local & 7;
      const int r = rp + 32 + (kt >= 2) * 32 + (kt >= 3) * 32;
      soff[it] = r * 128 + kt * 32 + ((c ^ (rp & 7)) << 2);
    } else {
      soff[it] = 0;
    }
  }
}

__device__ __forceinline__ void issue_A(const float* __restrict__ Al,
                                        float* __restrict__ Ast,
                                        const int (&soff)[8], int tid) {
#pragma unroll
  for (int it = 0; it < 8; ++it) {
    if (it < 7 || tid < 64)  // 2304 = 7*320 + 64 (wave 0 only on last iter)
      gload_lds16(Al + soff[it], Ast + (tid + it * 320) * 4);
  }
}

// staged B-fragment read (nt>=2): two swizzled 16B LDS reads + split
__device__ __forceinline__ void read_staged(const float* __restrict__ Ast,
                                            int nt, int kt, int lr, int q,
                                            f16x8& ch, f16x8& cl) {
  const int rp = nt * 16 + lr - (32 + (kt >= 2) * 32 + (kt >= 3) * 32);
  const float* pb =
      Ast + ((kt >= 1) * 3072 + (kt >= 2) * 3072 + (kt >= 3) * 2048) + rp * 32;
  float raw[8];
  *(float4*)&raw[0] = *(const float4*)(pb + (((2 * q + 0) ^ (rp & 7)) << 2));
  *(float4*)&raw[4] = *(const float4*)(pb + (((2 * q + 1) ^ (rp & 7)) << 2));
  split8(raw, ch, cl);
}

// ---------------------------------------------------------------------------
// chain_step (b16 global B path) — used by ks_np. Unchanged math.
// EXTRA==2: w-rows += w_add f32 [n][32b] (aux0)
template <int EXTRA>
__device__ __forceinline__ void chain_step_b16(const f16* __restrict__ Bh16,
                                               const f16* __restrict__ Bl16,
                                               const float* __restrict__ aux0,
                                               f16* __restrict__ Ph,
                                               f16* __restrict__ Pl,
                                               int wv, int mt) {
  const int lane = threadIdx.x & 63;
  const int lr = lane & 15, q = lane >> 4;
  const bool wrow = (mt >= 8);
  const int ktA0 = wrow ? 0 : (mt >> 1);
  f16x8 ah[4], al[4];
#pragma unroll
  for (int kt = 0; kt < 4; ++kt) {
    if (kt >= ktA0) {
      const int off = (wv * 16 + lr) * LDK + kt * 32 + q * 8;
      ah[kt] = *(const f16x8*)(Ph + off);
      al[kt] = *(const f16x8*)(Pl + off);
    }
  }
  f32x4 acc[8];
#pragma unroll
  for (int nt = 0; nt < 8; ++nt) acc[nt] = (f32x4){0.f, 0.f, 0.f, 0.f};

  f16x8 b16h[2][4], b16l[2][4];
  auto loadB = [&](int nt, int s) {
#pragma unroll
    for (int kt = 0; kt < 4; ++kt) {
      if (kt >= ktA0 && kt <= (nt >> 1)) {
        const int o = (nt * 16 + lr) * 128 + kt * 32 + q * 8;
        b16h[s][kt] = *(const f16x8*)(Bh16 + o);
        b16l[s][kt] = *(const f16x8*)(Bl16 + o);
      }
    }
  };

  if (wrow || mt == 0) loadB(0, 0);
#pragma unroll
  for (int nt = 0; nt < 8; ++nt) {
    const int cur = nt & 1;
    if (nt < 7 && (wrow || (nt + 1) >= mt)) loadB(nt + 1, cur ^ 1);
    if (wrow || nt >= mt) {
#pragma unroll
      for (int kt = 0; kt < 4; ++kt)
        if (kt >= ktA0 && kt <= (nt >> 1))
          acc[nt] = mfma3(ah[kt], al[kt], b16h[cur][kt], b16l[cur][kt], acc[nt]);
    }
  }
  __syncthreads();
#pragma unroll
  for (int nt = 0; nt < 8; ++nt) {
    if (!(wrow || nt >= mt)) continue;
    float v[4] = {acc[nt][0], acc[nt][1], acc[nt][2], acc[nt][3]};
    if (wrow) {
      const int b0 = (mt - 8) * 16 + q * 4;
      if (EXTRA == 2) {
        const float4 w4 = *(const float4*)(aux0 + (nt * 16 + lr) * 32 + b0);
        v[0] += w4.x; v[1] += w4.y; v[2] += w4.z; v[3] += w4.w;
      }
    }
#pragma unroll
    for (int r = 0; r < 4; ++r) {
      const int o = (wv * 16 + q * 4 + r) * LDK + nt * 16 + lr;
      const f16 hh = (f16)v[r];
      Ph[o] = hh;
      Pl[o] = (f16)(v[r] - (float)hh);
    }
  }
  __syncthreads();
}

// ---------------------------------------------------------------------------
// chain_step_k1: B operand from staged LDS (nt>=2) + direct regs (nt<2).
// Issues next step's A staging between the two barriers. EXTRA==1 semantics.
__device__ __forceinline__ void chain_step_k1(const float* __restrict__ Acur,
                                              const float* __restrict__ Anext,
                                              const float* __restrict__ x32,
                                              const float* __restrict__ Bvl,
                                              f16* __restrict__ Ph,
                                              f16* __restrict__ Pl,
                                              float* __restrict__ Ast,
                                              const int (&soff)[8],
                                              int wv, int mt) {
  const int tid = threadIdx.x;
  const int lane = tid & 63, lr = lane & 15, q = lane >> 4;
  const bool wrow = (mt >= 8);
  const int ktA0 = wrow ? 0 : (mt >> 1);
  f16x8 ah[4], al[4];
#pragma unroll
  for (int kt = 0; kt < 4; ++kt) {
    if (kt >= ktA0) {
      const int off = (wv * 16 + lr) * LDK + kt * 32 + q * 8;
      ah[kt] = *(const f16x8*)(Ph + off);
      al[kt] = *(const f16x8*)(Pl + off);
    }
  }
  // direct rows 0..31 (kt0 only), issued early
  const bool need0 = wrow || mt == 0;
  const bool need1 = wrow || mt <= 1;
  float dir0[8], dir1[8];
  if (need0) {
    const float* p = Acur + lr * 128 + q * 8;
    *(float4*)&dir0[0] = *(const float4*)p;
    *(float4*)&dir0[4] = *(const float4*)(p + 4);
  }
  if (need1) {
    const float* p = Acur + (16 + lr) * 128 + q * 8;
    *(float4*)&dir1[0] = *(const float4*)p;
    *(float4*)&dir1[4] = *(const float4*)(p + 4);
  }
  f32x4 acc[8];
#pragma unroll
  for (int nt = 0; nt < 8; ++nt) acc[nt] = (f32x4){0.f, 0.f, 0.f, 0.f};
#pragma unroll
  for (int nt = 2; nt < 8; ++nt) {
    if (wrow || nt >= mt) {
#pragma unroll
      for (int kt = 0; kt < 4; ++kt) {
        if (kt >= ktA0 && kt <= (nt >> 1)) {
          f16x8 ch, cl;
          read_staged(Ast, nt, kt, lr, q, ch, cl);
          acc[nt] = mfma3(ah[kt], al[kt], ch, cl, acc[nt]);
        }
      }
    }
  }
  if (need0) {
    f16x8 ch, cl;
    split8(dir0, ch, cl);
    acc[0] = mfma3(ah[0], al[0], ch, cl, acc[0]);
  }
  if (need1) {
    f16x8 ch, cl;
    split8(dir1, ch, cl);
    acc[1] = mfma3(ah[0], al[0], ch, cl, acc[1]);
  }
  __syncthreads();  // all Ast reads + state reads complete
  if (Anext) issue_A(Anext, Ast, soff, tid);  // async overwrite, drained at next barrier
#pragma unroll
  for (int nt = 0; nt < 8; ++nt) {
    if (!(wrow || nt >= mt)) continue;
    float v[4] = {acc[nt][0], acc[nt][1], acc[nt][2], acc[nt][3]};
    if (wrow) {
      const int b0 = (mt - 8) * 16 + q * 4;
      const float4 x4 = *(const float4*)(x32 + b0);
      const float bn = Bvl[nt * 16 + lr];
      v[0] += bn * x4.x; v[1] += bn * x4.y; v[2] += bn * x4.z; v[3] += bn * x4.w;
    }
#pragma unroll
    for (int r = 0; r < 4; ++r) {
      const int o = (wv * 16 + q * 4 + r) * LDK + nt * 16 + lr;
      const f16 hh = (f16)v[r];
      Ph[o] = hh;
      Pl[o] = (f16)(v[r] - (float)hh);
    }
  }
  __syncthreads();
}

// copy P' (= result^T in LDS) out as PLAIN M (f16 hi/lo) + w (f32 [n][32]).
// Triangular: storage vector [i][y0..y0+7] is skipped (left garbage) when
// (y0>>5) > (i>>5); all readers are tile-gated or zero-fill that region.
__device__ __forceinline__ void chain_copyout(const f16* __restrict__ Ph,
                                              const f16* __restrict__ Pl, int h,
                                              f16* __restrict__ oMh,
                                              f16* __restrict__ oMl,
                                              float* __restrict__ oW) {
  const int tid = threadIdx.x;
  for (int t = tid; t < 1024; t += 320) {
    const int i = t >> 3;
    const int slot = (t >> 1) & 3;
    const int half = t & 1;
    const int mtg = slot2mt(h, slot);
    const int y0 = mtg * 16 + half * 8;
    if ((y0 >> 5) > (i >> 5)) continue;  // zero tile: skip store
    f16x8 hv, lv;
#pragma unroll
    for (int e = 0; e < 8; ++e) {
      hv[e] = Ph[(slot * 16 + half * 8 + e) * LDK + i];
      lv[e] = Pl[(slot * 16 + half * 8 + e) * LDK + i];
    }
    *(f16x8*)(oMh + i * 128 + y0) = hv;
    *(f16x8*)(oMl + i * 128 + y0) = lv;
  }
  for (int t = tid; t < 512; t += 320) {
    const int n = t >> 2, b4 = (t & 3) * 4;
    float4 o;
    float* po = (float*)&o;
#pragma unroll
    for (int e = 0; e < 4; ++e)
      po[e] = (float)Ph[(64 + b4 + e) * LDK + n] + (float)Pl[(64 + b4 + e) * LDK + n];
    *(float4*)(oW + n * 32 + h * 16 + b4) = o;
  }
}

// P'-init: load prev node's plain M + W into LDS (transposed). Trailing barrier.
// Triangular: loads only (y0>>5) <= (k>>5) vectors; zero-fills the rest.
__device__ __forceinline__ void load_prev_to_P(const f16* pMh, const f16* pMl,
                                               const float* pW, int h,
                                               f16* Ph, f16* Pl) {
  const int tid = threadIdx.x;
  for (int t = tid; t < 1024; t += 320) {
    const int k = t >> 3, u = t & 7;
    const int slot = u >> 1, half = u & 1;
    const int mtg = slot2mt(h, slot);
    const int y0 = mtg * 16 + half * 8;
    f16x8 hv, lv;
    if ((y0 >> 5) <= (k >> 5)) {
      hv = *(const f16x8*)(pMh + k * 128 + y0);
      lv = *(const f16x8*)(pMl + k * 128 + y0);
    } else {
#pragma unroll
      for (int e = 0; e < 8; ++e) { hv[e] = (f16)0.f; lv[e] = (f16)0.f; }
    }
#pragma unroll
    for (int e = 0; e < 8; ++e) {
      Ph[(slot * 16 + half * 8 + e) * LDK + k] = hv[e];
      Pl[(slot * 16 + half * 8 + e) * LDK + k] = lv[e];
    }
  }
  for (int t = tid; t < 2048; t += 320) {
    const int n = t >> 4, b = t & 15;
    const float wv0 = pW[n * 32 + h * 16 + b];
    const f16 hh = (f16)wv0;
    Ph[(64 + b) * LDK + n] = hh;
    Pl[(64 + b) * LDK + n] = (f16)(wv0 - (float)hh);
  }
  __syncthreads();
}

// ---------------------------------------------------------------------------
// state_step_h (b16 path): 16-row state <- state * B^T (+w add). Works with
// >=256 threads; waves 0..3 compute, extra waves barrier only.
__device__ __forceinline__ void state_step_h_b16(const f16* __restrict__ Bh16,
                                                 const f16* __restrict__ Bl16,
                                                 const float* __restrict__ aux0,
                                                 f16* __restrict__ Sh,
                                                 f16* __restrict__ Sl, int h) {
  const int tid = threadIdx.x;
  const int wv4 = tid >> 6;
  const bool act = (wv4 < 4);
  const int wv = wv4 & 3;
  const int lane = tid & 63, lr = lane & 15, q = lane >> 4;
  const int nts[2] = {wv, 7 - wv};
  const int ktAmax = (7 - wv) >> 1;
  f16x8 ah[4], al[4];
  f16x8 bh[2][4], bl[2][4];
  f32x4 acc[2];
  if (act) {
#pragma unroll
    for (int kt = 0; kt < 4; ++kt)
      if (kt <= ktAmax) {
        const int off = lr * LDK + kt * 32 + q * 8;
        ah[kt] = *(const f16x8*)(Sh + off);
        al[kt] = *(const f16x8*)(Sl + off);
      }
#pragma unroll
    for (int ni = 0; ni < 2; ++ni) {
      const int nt = nts[ni];
#pragma unroll
      for (int kt = 0; kt < 4; ++kt)
        if (kt <= (nt >> 1)) {
          const int o = (nt * 16 + lr) * 128 + kt * 32 + q * 8;
          bh[ni][kt] = *(const f16x8*)(Bh16 + o);
          bl[ni][kt] = *(const f16x8*)(Bl16 + o);
        }
    }
#pragma unroll
    for (int ni = 0; ni < 2; ++ni) acc[ni] = (f32x4){0.f, 0.f, 0.f, 0.f};
#pragma unroll
    for (int ni = 0; ni < 2; ++ni) {
      const int nt = nts[ni];
#pragma unroll
      for (int kt = 0; kt < 4; ++kt)
        if (kt <= (nt >> 1))
          acc[ni] = mfma3(ah[kt], al[kt], bh[ni][kt], bl[ni][kt], acc[ni]);
    }
  }
  __syncthreads();
  if (act) {
#pragma unroll
    for (int ni = 0; ni < 2; ++ni) {
      const int nt = nts[ni];
      float v[4] = {acc[ni][0], acc[ni][1], acc[ni][2], acc[ni][3]};
      const int bq = q * 4;
      const float4 w4 = *(const float4*)(aux0 + (nt * 16 + lr) * 32 + h * 16 + bq);
      v[0] += w4.x; v[1] += w4.y; v[2] += w4.z; v[3] += w4.w;
#pragma unroll
      for (int r = 0; r < 4; ++r) {
        const int o = (bq + r) * LDK + nt * 16 + lr;
        const f16 hh = (f16)v[r];
        Sh[o] = hh;
        Sl[o] = (f16)(v[r] - (float)hh);
      }
    }
  }
  __syncthreads();
}

// state_step_h_staged: B from staged LDS (nt>=2) + direct regs (nt<2 on wv<2).
// Issues next step's A staging between barriers. EXTRA==1 semantics + out.
__device__ __forceinline__ void state_step_h_staged(
    const float* __restrict__ Acur, const float* __restrict__ Anext,
    const float* __restrict__ x32, const float* __restrict__ Bvl,
    f16* __restrict__ Sh, f16* __restrict__ Sl, float* __restrict__ outp,
    int h, float* __restrict__ Ast, const int (&soff)[8]) {
  const int tid = threadIdx.x;
  const int wv4 = tid >> 6;
  const bool act = (wv4 < 4);
  const int wv = wv4 & 3;
  const int lane = tid & 63, lr = lane & 15, q = lane >> 4;
  const int ntL = wv, ntH = 7 - wv;
  f32x4 accL = (f32x4){0.f, 0.f, 0.f, 0.f}, accH = accL;
  if (act) {
    const int ktAmax = ntH >> 1;
    f16x8 ah[4], al[4];
#pragma unroll
    for (int kt = 0; kt < 4; ++kt)
      if (kt <= ktAmax) {
        const int off = lr * LDK + kt * 32 + q * 8;
        ah[kt] = *(const f16x8*)(Sh + off);
        al[kt] = *(const f16x8*)(Sl + off);
      }
    float dir[8];
    if (wv < 2) {  // ntL in {0,1}: direct kt0 rows
      const float* p = Acur + (ntL * 16 + lr) * 128 + q * 8;
      *(float4*)&dir[0] = *(const float4*)p;
      *(float4*)&dir[4] = *(const float4*)(p + 4);
    }
    // staged high nt (4..7)
#pragma unroll
    for (int kt = 0; kt < 4; ++kt) {
      if (kt <= (ntH >> 1)) {
        f16x8 ch, cl;
        read_staged(Ast, ntH, kt, lr, q, ch, cl);
        accH = mfma3(ah[kt], al[kt], ch, cl, accH);
      }
    }
    if (wv >= 2) {  // ntL in {2,3}: staged
#pragma unroll
      for (int kt = 0; kt < 4; ++kt) {
        if (kt <= (ntL >> 1)) {
          f16x8 ch, cl;
          read_staged(Ast, ntL, kt, lr, q, ch, cl);
          accL = mfma3(ah[kt], al[kt], ch, cl, accL);
        }
      }
    } else {
      f16x8 ch, cl;
      split8(dir, ch, cl);
      accL = mfma3(ah[0], al[0], ch, cl, accL);
    }
  }
  __syncthreads();
  if (Anext) issue_A(Anext, Ast, soff, tid);
  if (act) {
#pragma unroll
    for (int ni = 0; ni < 2; ++ni) {
      const int nt = (ni == 0) ? ntL : ntH;
      const f32x4 a = (ni == 0) ? accL : accH;
      float v[4] = {a[0], a[1], a[2], a[3]};
      const int bq = q * 4;
      const float4 x4 = *(const float4*)(x32 + h * 16 + bq);
      const float bn = Bvl[nt * 16 + lr];
      v[0] += bn * x4.x; v[1] += bn * x4.y; v[2] += bn * x4.z; v[3] += bn * x4.w;
      if (outp) {
#pragma unroll
        for (int r = 0; r < 4; ++r)
          outp[(h * 16 + bq + r) * 128 + nt * 16 + lr] = v[r];
      }
#pragma unroll
      for (int r = 0; r < 4; ++r) {
        const int o = (bq + r) * LDK + nt * 16 + lr;
        const f16 hh = (f16)v[r];
        Sh[o] = hh;
        Sl[o] = (f16)(v[r] - (float)hh);
      }
    }
  }
  __syncthreads();
}

// ---------------------------------------------------------------------------
// K1: chunk units. grid 512 (c = bid>>1, h = bid&1), 320 threads. writes set A.
__global__ __launch_bounds__(320) void k1_chunks(const float* __restrict__ A,
                                                 const float* __restrict__ x,
                                                 const float* __restrict__ Bv,
                                                 f16* __restrict__ Mh,
                                                 f16* __restrict__ Ml,
                                                 float* __restrict__ Wf) {
  __shared__ f16 Ph[80 * LDK], Pl[80 * LDK];
  __shared__ float Ast[9216];
  const int tid = threadIdx.x;
  const int c = blockIdx.x >> 1, h = blockIdx.x & 1;
  const int l0 = 4 * c;
  int soff[8];
  compute_soff(tid, soff);
  issue_A(A + (size_t)(l0 + 1) * 16384, Ast, soff, tid);  // stage step 1 early
  const float* A0 = A + (size_t)l0 * 16384;
  for (int t = tid; t < 2048; t += 320) {
    const int k = t >> 4, u = t & 15;
    const int slot = u >> 2, fo = (u & 3) * 4;
    const int mtg = slot2mt(h, slot);
    const int y = mtg * 16 + fo;
    float vv[4];
    if ((y >> 5) <= (k >> 5)) {  // triangular: upper tiles are zero
      const float4 v = *(const float4*)(A0 + k * 128 + y);
      vv[0] = v.x; vv[1] = v.y; vv[2] = v.z; vv[3] = v.w;
    } else {
      vv[0] = vv[1] = vv[2] = vv[3] = 0.f;
    }
#pragma unroll
    for (int e = 0; e < 4; ++e) {
      const f16 hh = (f16)vv[e];
      Ph[(slot * 16 + fo + e) * LDK + k] = hh;
      Pl[(slot * 16 + fo + e) * LDK + k] = (f16)(vv[e] - (float)hh);
    }
  }
  for (int t = tid; t < 512; t += 320) {
    const int b = t >> 5, n4 = (t & 31) * 4;
    const float xb = x[l0 * 32 + h * 16 + b];
#pragma unroll
    for (int e = 0; e < 4; ++e) {
      const float u = xb * Bv[l0 * 128 + n4 + e];
      const f16 hh = (f16)u;
      Ph[(64 + b) * LDK + n4 + e] = hh;
      Pl[(64 + b) * LDK + n4 + e] = (f16)(u - (float)hh);
    }
  }
  __syncthreads();  // drains vmcnt: staged A for step 1 ready
  const int wv = tid >> 6;
  const int mt = (wv == 4) ? (8 + h) : slot2mt(h, wv);
  chain_step_k1(A + (size_t)(l0 + 1) * 16384, A + (size_t)(l0 + 2) * 16384,
                x + (l0 + 1) * 32, Bv + (l0 + 1) * 128, Ph, Pl, Ast, soff, wv, mt);
  chain_step_k1(A + (size_t)(l0 + 2) * 16384, A + (size_t)(l0 + 3) * 16384,
                x + (l0 + 2) * 32, Bv + (l0 + 2) * 128, Ph, Pl, Ast, soff, wv, mt);
  chain_step_k1(A + (size_t)(l0 + 3) * 16384, nullptr,
                x + (l0 + 3) * 32, Bv + (l0 + 3) * 128, Ph, Pl, Ast, soff, wv, mt);
  chain_copyout(Ph, Pl, h, Mh + (size_t)c * 16384, Ml + (size_t)c * 16384,
                Wf + (size_t)c * 4096);
}

// ---------------------------------------------------------------------------
// Passthrough-free Kogge-Stone level D over within-group (16) prefixes.
// grid 512, 320 thr; blocks with j<D exit. Source buffer per node class:
// L = min(pow2floor(j'), D/2); L in {0,2,8} -> set A, {1,4} -> set B.
template <int D>
__global__ __launch_bounds__(320) void ks_np(const f16* MhA, const f16* MlA,
                                             const float* WA, const f16* MhB,
                                             const f16* MlB, const float* WB,
                                             f16* oMh, f16* oMl, float* oW) {
  const int node = blockIdx.x >> 1, h = blockIdx.x & 1;
  const int j = node & 15;
  if (j < D) return;  // no passthrough copies
  __shared__ f16 Ph[80 * LDK], Pl[80 * LDK];
  const int tid = threadIdx.x;
  const int prev = node - D;
  const int jp = j - D;
  int Lp = 0;
  if (jp > 0) {
    Lp = 1 << (31 - __clz(jp));
    if (Lp > (D >> 1)) Lp = D >> 1;
  }
  const bool pB = (Lp == 1 || Lp == 4);
  const f16* pMh = (pB ? MhB : MhA) + (size_t)prev * 16384;
  const f16* pMl = (pB ? MlB : MlA) + (size_t)prev * 16384;
  const float* pW = (pB ? WB : WA) + (size_t)prev * 4096;
  // own node: latest level is D/2 -> A for D in {1,4}, B for D in {2,8}
  constexpr bool oB = (D == 2 || D == 8);
  const f16* nMh = (oB ? MhB : MhA) + (size_t)node * 16384;
  const f16* nMl = (oB ? MlB : MlA) + (size_t)node * 16384;
  const float* nW = (oB ? WB : WA) + (size_t)node * 4096;

  load_prev_to_P(pMh, pMl, pW, h, Ph, Pl);
  const int wv = tid >> 6;
  const int mt = (wv == 4) ? (8 + h) : slot2mt(h, wv);
  chain_step_b16<2>(nMh, nMl, nW, Ph, Pl, wv, mt);
  chain_copyout(Ph, Pl, h, oMh + (size_t)node * 16384,
                oMl + (size_t)node * 16384, oW + (size_t)node * 4096);
}

// ---------------------------------------------------------------------------
// gscan: serial Horner state scan over the 16 group totals (A-set nodes
// 16t+15 after level 8). grid 32 (g = bid>>1, h = bid&1), 256 threads.
// Writes entry states Ef[g] as f32 [n][32] (g=0 -> zeros).
__global__ __launch_bounds__(256) void gscan(const f16* __restrict__ MhA,
                                             const f16* __restrict__ MlA,
                                             const float* __restrict__ WA,
                                             float* __restrict__ Ef) {
  __shared__ f16 Sh[16 * LDK], Sl[16 * LDK];
  const int g = blockIdx.x >> 1, h = blockIdx.x & 1;
  const int tid = threadIdx.x;
  for (int t = tid; t < 16 * LDK; t += 256) { Sh[t] = (f16)0.f; Sl[t] = (f16)0.f; }
  __syncthreads();
#pragma unroll 1
  for (int t = 0; t < g; ++t) {
    const size_t nd = (size_t)(16 * t + 15);
    state_step_h_b16(MhA + nd * 16384, MlA + nd * 16384, WA + nd * 4096,
                     Sh, Sl, h);
  }
  for (int t = tid; t < 2048; t += 256) {
    const int row = t & 15, n = t >> 4;
    Ef[(size_t)g * 4096 + n * 32 + h * 16 + row] =
        (float)Sh[row * LDK + n] + (float)Sl[row * LDK + n];
  }
}

// ---------------------------------------------------------------------------
// K3 h-split: grid 512 (c = bid>>1, h = bid&1), 320 thr, 16 batch rows each.
// entry = Ef[g] (f32); if j>0 apply chunk prefix c-1; replay 4 timesteps.
__global__ __launch_bounds__(320) void k3h(const float* __restrict__ A,
                                           const float* __restrict__ x,
                                           const float* __restrict__ Bv,
                                           const f16* __restrict__ MhA,
                                           const f16* __restrict__ MlA,
                                           const float* __restrict__ WA,
                                           const f16* __restrict__ MhB,
                                           const f16* __restrict__ MlB,
                                           const float* __restrict__ WB,
                                           const float* __restrict__ Ef,
                                           float* __restrict__ out) {
  __shared__ f16 Sh[16 * LDK], Sl[16 * LDK];
  __shared__ float Ast[9216];
  const int tid = threadIdx.x;
  const int c = blockIdx.x >> 1, h = blockIdx.x & 1;
  const int g = c >> 4, j = c & 15;
  int soff[8];
  compute_soff(tid, soff);
  issue_A(A + (size_t)(4 * c) * 16384, Ast, soff, tid);  // stage t4=0 early
  const float* Ew = Ef + (size_t)g * 4096;
  for (int tt = tid; tt < 2048; tt += 320) {
    const int row = tt & 15, n = tt >> 4;
    const float v = Ew[n * 32 + h * 16 + row];
    const f16 hh = (f16)v;
    Sh[row * LDK + n] = hh;
    Sl[row * LDK + n] = (f16)(v - (float)hh);
  }
  __syncthreads();  // drains vmcnt: staged A for t4=0 ready
  if (j > 0) {
    // chunk-final map on j' = j-1: {0,2,3,8..14} -> A, {1,4..7} -> B
    const int nd = c - 1, jp = j - 1;
    const bool inB = (jp == 1 || (jp >= 4 && jp <= 7));
    const f16* mh = (inB ? MhB : MhA) + (size_t)nd * 16384;
    const f16* ml = (inB ? MlB : MlA) + (size_t)nd * 16384;
    const float* w = (inB ? WB : WA) + (size_t)nd * 4096;
    state_step_h_b16(mh, ml, w, Sh, Sl, h);
  }
#pragma unroll 1
  for (int t4 = 0; t4 < 4; ++t4) {
    const int l = 4 * c + t4;
    const float* Anext = (t4 < 3) ? A + (size_t)(l + 1) * 16384 : nullptr;
    state_step_h_staged(A + (size_t)l * 16384, Anext, x + l * 32, Bv + l * 128,
                        Sh, Sl, out + (size_t)l * 4096, h, Ast, soff);
  }
}

// ---------------------------------------------------------------------------
extern "C" void kernel_launch(void* const* d_in, const int* in_sizes, int n_in,
                              void* d_out, int out_size, void* d_ws, size_t ws_size,
                              hipStream_t stream) {
  const float* x  = (const float*)d_in[0];  // (1024, 32)
  const float* A  = (const float*)d_in[1];  // (1024, 128, 128) lower-triangular
  const float* Bv = (const float*)d_in[2];  // (1024, 128)
  float* out = (float*)d_out;               // (1024, 32, 128)

  // set A
  f16* MhA = (f16*)d_ws;                    // 256*16384 f16
  f16* MlA = MhA + 256 * 16384;
  float* WA = (float*)(MlA + 256 * 16384);  // 256*4096 f32
  // set B
  f16* MhB = (f16*)(WA + 256 * 4096);
  f16* MlB = MhB + 256 * 16384;
  float* WB = (float*)(MlB + 256 * 16384);
  // entry states (f32)
  float* Ef = WB + 256 * 4096;              // 16*4096 f32; total ~42.2 MB

  k1_chunks<<<512, 320, 0, stream>>>(A, x, Bv, MhA, MlA, WA);
  ks_np<1><<<512, 320, 0, stream>>>(MhA, MlA, WA, MhB, MlB, WB, MhB, MlB, WB);
  ks_np<2><<<512, 320, 0, stream>>>(MhA, MlA, WA, MhB, MlB, WB, MhA, MlA, WA);
  ks_np<4><<<512, 320, 0, stream>>>(MhA, MlA, WA, MhB, MlB, WB, MhB, MlB, WB);
  ks_np<8><<<512, 320, 0, stream>>>(MhA, MlA, WA, MhB, MlB, WB, MhA, MlA, WA);
  gscan<<<32, 256, 0, stream>>>(MhA, MlA, WA, Ef);
  k3h<<<512, 320, 0, stream>>>(A, x, Bv, MhA, MlA, WA, MhB, MlB, WB, Ef, out);
}